// Round 1
// baseline (1192.680 us; speedup 1.0000x reference)
//
#include <hip/hip_runtime.h>
#include <hip/hip_bf16.h>
#include <stdint.h>

using bf16 = __hip_bfloat16;
using short8 = __attribute__((ext_vector_type(8))) short;   // 8 bf16 (4 VGPRs)
using f32x4 = __attribute__((ext_vector_type(4))) float;    // 4 fp32 acc

#define T_SEQ 2048
#define DMODEL 1024
#define NHEAD 16
#define DHEAD 64
#define DFF 4096

struct __align__(8) bf16x4 { bf16 x, y, z, w; };

__device__ __forceinline__ void async_cp16(const bf16* g, bf16* l) {
  __builtin_amdgcn_global_load_lds(
      (const __attribute__((address_space(1))) uint32_t*)g,
      (__attribute__((address_space(3))) uint32_t*)l, 16, 0, 0);
}

// ---------------- transpose + fp32->bf16 convert: src(R,C) -> dst(C,R) ----------------
__global__ __launch_bounds__(256) void transpose_cvt(const float* __restrict__ src,
                                                     bf16* __restrict__ dst,
                                                     int R, int C) {
  __shared__ float tile[32][33];
  int bx = blockIdx.x * 32;  // col of src
  int by = blockIdx.y * 32;  // row of src
  int tx = threadIdx.x, ty = threadIdx.y;  // 32 x 8
#pragma unroll
  for (int r = 0; r < 32; r += 8)
    tile[ty + r][tx] = src[(long)(by + ty + r) * C + bx + tx];
  __syncthreads();
#pragma unroll
  for (int r = 0; r < 32; r += 8)
    dst[(long)(bx + ty + r) * R + by + tx] = __float2bfloat16(tile[tx][ty + r]);
}

// ---------------- fp32 -> bf16 elementwise (x4) ----------------
__global__ __launch_bounds__(256) void cvt_bf16(const float* __restrict__ src,
                                                bf16* __restrict__ dst, int n4) {
  int idx = blockIdx.x * 256 + threadIdx.x;
  if (idx < n4) {
    float4 v = ((const float4*)src)[idx];
    bf16x4 o{__float2bfloat16(v.x), __float2bfloat16(v.y),
             __float2bfloat16(v.z), __float2bfloat16(v.w)};
    ((bf16x4*)dst)[idx] = o;
  }
}

// ---------------- LayerNorm (D=1024) -> bf16, one block per row ----------------
__global__ __launch_bounds__(256) void ln_cvt(const float* __restrict__ x,
                                              const float* __restrict__ g,
                                              const float* __restrict__ b,
                                              bf16* __restrict__ out) {
  int row = blockIdx.x;
  int tid = threadIdx.x;
  float4 v = ((const float4*)(x + (long)row * DMODEL))[tid];
  float s = v.x + v.y + v.z + v.w;
  float s2 = v.x * v.x + v.y * v.y + v.z * v.z + v.w * v.w;
#pragma unroll
  for (int off = 32; off > 0; off >>= 1) {
    s += __shfl_down(s, off);
    s2 += __shfl_down(s2, off);
  }
  __shared__ float ss[4], ss2[4];
  int wave = tid >> 6, lane = tid & 63;
  if (lane == 0) { ss[wave] = s; ss2[wave] = s2; }
  __syncthreads();
  s = ss[0] + ss[1] + ss[2] + ss[3];
  s2 = ss2[0] + ss2[1] + ss2[2] + ss2[3];
  float mean = s * (1.0f / DMODEL);
  float var = s2 * (1.0f / DMODEL) - mean * mean;
  float rstd = rsqrtf(var + 1e-5f);
  float4 gg = ((const float4*)g)[tid];
  float4 bb = ((const float4*)b)[tid];
  bf16x4 o{__float2bfloat16((v.x - mean) * rstd * gg.x + bb.x),
           __float2bfloat16((v.y - mean) * rstd * gg.y + bb.y),
           __float2bfloat16((v.z - mean) * rstd * gg.z + bb.z),
           __float2bfloat16((v.w - mean) * rstd * gg.w + bb.w)};
  ((bf16x4*)(out + (long)row * DMODEL))[tid] = o;
}

// ---------------- generic MFMA GEMM: C(M,N) = A(M,K) * Bt(N,K)^T ----------------
template <int BN, class Epi>
__global__ __launch_bounds__(256) void gemm_bt(const bf16* __restrict__ A,
                                               const bf16* __restrict__ Bt,
                                               int M, int N, int K,
                                               long aZstride, long bZstride, Epi epi) {
  constexpr int BM = 128;
  constexpr int BK = 32;
  constexpr int NT = BN / 32;
  __shared__ bf16 As[BM * BK];
  __shared__ bf16 Bs[BN * BK];

  const int bm = blockIdx.y, bn = blockIdx.x, z = blockIdx.z;
  if (epi.skip(bm, bn)) return;
  const bf16* Ab = A + (long)z * aZstride;
  const bf16* Bb = Bt + (long)z * bZstride;

  const int tid = threadIdx.x;
  const int lane = tid & 63;
  const int wave = tid >> 6;
  const int wr = wave >> 1;
  const int wc = wave & 1;
  const int kEnd = epi.kmax(bm, bn, K);

  const f32x4 zero4 = {0.f, 0.f, 0.f, 0.f};
  f32x4 acc[4][NT];
#pragma unroll
  for (int mt = 0; mt < 4; ++mt)
#pragma unroll
    for (int nt = 0; nt < NT; ++nt) acc[mt][nt] = zero4;

  const int sr = tid >> 2;         // staging row within 64-row round
  const int sc = (tid & 3) * 8;    // staging col
  const bf16* aG0 = Ab + (long)(bm * BM + sr) * K + sc;
  const bf16* aG1 = Ab + (long)(bm * BM + 64 + sr) * K + sc;
  bf16* aL0 = As + tid * 8;
  bf16* aL1 = As + 2048 + tid * 8;
  const bf16* bG0 = Bb + (long)(bn * BN + sr) * K + sc;
  bf16* bL0 = Bs + tid * 8;
  const bf16* bG1 = Bb + (long)(bn * BN + 64 + sr) * K + sc;  // BN==128 only
  bf16* bL1 = Bs + 2048 + tid * 8;

  const int aRow = wr * 64 + (lane & 15);
  const int bRow = wc * (BN / 2) + (lane & 15);
  const int kq = (lane >> 4) * 8;

  for (int k0 = 0; k0 < kEnd; k0 += BK) {
    __syncthreads();
    async_cp16(aG0, aL0);
    async_cp16(aG1, aL1);
    async_cp16(bG0, bL0);
    if constexpr (BN == 128) async_cp16(bG1, bL1);
    aG0 += BK; aG1 += BK; bG0 += BK;
    if constexpr (BN == 128) bG1 += BK;
    __syncthreads();
    short8 af[4], bfr[NT];
#pragma unroll
    for (int mt = 0; mt < 4; ++mt)
      af[mt] = *(const short8*)(As + (aRow + mt * 16) * BK + kq);
#pragma unroll
    for (int nt = 0; nt < NT; ++nt)
      bfr[nt] = *(const short8*)(Bs + (bRow + nt * 16) * BK + kq);
#pragma unroll
    for (int mt = 0; mt < 4; ++mt)
#pragma unroll
      for (int nt = 0; nt < NT; ++nt)
        acc[mt][nt] = __builtin_amdgcn_mfma_f32_16x16x32_bf16(af[mt], bfr[nt],
                                                              acc[mt][nt], 0, 0, 0);
  }

  const int rBase = (lane >> 4) * 4;
  const int cOff = lane & 15;
#pragma unroll
  for (int mt = 0; mt < 4; ++mt) {
#pragma unroll
    for (int nt = 0; nt < NT; ++nt) {
      int row = bm * BM + wr * 64 + mt * 16 + rBase;
      int col = bn * BN + wc * (BN / 2) + nt * 16 + cOff;
      f32x4 v = acc[mt][nt];
#pragma unroll
      for (int r = 0; r < 4; ++r) epi.store(z, row + r, col, v[r]);
    }
  }
}

// ---------------- epilogues ----------------
struct EpiQKV {
  bf16 *Q1, *Q2, *Kb, *Vt;
  const float *rwb, *rrb;
  __device__ bool skip(int, int) const { return false; }
  __device__ int kmax(int, int, int K) const { return K; }
  __device__ void store(int, int row, int col, float v) const {
    int n = (col >> 6) & 15, d = col & 63;
    long hoff = ((long)n * T_SEQ + row) * DHEAD + d;
    if (col < DMODEL) {
      Q1[hoff] = __float2bfloat16(v + rwb[col]);
      Q2[hoff] = __float2bfloat16(v + rrb[col]);
    } else if (col < 2 * DMODEL) {
      Kb[hoff] = __float2bfloat16(v);
    } else {
      Vt[((long)n * DHEAD + d) * T_SEQ + row] = __float2bfloat16(v);
    }
  }
};

struct EpiRk {
  bf16* Rk;
  __device__ bool skip(int, int) const { return false; }
  __device__ int kmax(int, int, int K) const { return K; }
  __device__ void store(int, int row, int col, float v) const {
    int n = col >> 6, d = col & 63;
    Rk[((long)n * T_SEQ + row) * DHEAD + d] = __float2bfloat16(v);
  }
};

struct EpiAC {
  bf16* out;
  __device__ bool skip(int bm, int bn) const { return bn > bm; }  // only j<=i needed
  __device__ int kmax(int, int, int K) const { return K; }
  __device__ void store(int z, int row, int col, float v) const {
    out[(long)z * T_SEQ * T_SEQ + (long)row * T_SEQ + col] = __float2bfloat16(v);
  }
};

struct EpiBD {
  bf16* out;
  // needed region: i + c >= T-1 -> keep bm+bn >= 15 (128-tiles)
  __device__ bool skip(int bm, int bn) const { return bm + bn < 15; }
  __device__ int kmax(int, int, int K) const { return K; }
  __device__ void store(int z, int row, int col, float v) const {
    out[(long)z * T_SEQ * T_SEQ + (long)row * T_SEQ + col] = __float2bfloat16(v);
  }
};

struct EpiPV {
  bf16* av;
  __device__ bool skip(int, int) const { return false; }
  __device__ int kmax(int bm, int, int K) const {
    int kl = (bm + 1) * 128;
    return kl < K ? kl : K;
  }
  __device__ void store(int z, int row, int col, float v) const {
    av[(long)row * DMODEL + z * DHEAD + col] = __float2bfloat16(v);
  }
};

struct EpiO {
  float* xws;
  const float* inp;
  __device__ bool skip(int, int) const { return false; }
  __device__ int kmax(int, int, int K) const { return K; }
  __device__ void store(int, int row, int col, float v) const {
    long idx = (long)row * DMODEL + col;
    xws[idx] = v + inp[idx];
  }
};

struct EpiFF1 {
  bf16* h;
  const float* b1;
  __device__ bool skip(int, int) const { return false; }
  __device__ int kmax(int, int, int K) const { return K; }
  __device__ void store(int, int row, int col, float v) const {
    h[(long)row * DFF + col] = __float2bfloat16(fmaxf(v + b1[col], 0.f));
  }
};

struct EpiFF2 {
  float* out;
  const float* b2;
  const float* xws;
  __device__ bool skip(int, int) const { return false; }
  __device__ int kmax(int, int, int K) const { return K; }
  __device__ void store(int, int row, int col, float v) const {
    long idx = (long)row * DMODEL + col;
    out[idx] = v + b2[col] + xws[idx];
  }
};

// ---------------- softmax over scores, write probs (fp32 out + bf16 for PV) ----------------
__global__ __launch_bounds__(256) void softmax_k(const bf16* __restrict__ AC,
                                                 const bf16* __restrict__ BD,
                                                 float* __restrict__ probs,
                                                 bf16* __restrict__ pb) {
  int i = blockIdx.x;
  int tid = threadIdx.x;
  int n = tid & 15, jj = tid >> 4;
  const float scale = 0.125f;  // 1/sqrt(64)
  const bf16* acr = AC + (long)n * T_SEQ * T_SEQ + (long)i * T_SEQ;
  const bf16* bdr = BD + (long)n * T_SEQ * T_SEQ + (long)i * T_SEQ + (T_SEQ - 1 - i);

  float m = -1e30f, l = 0.f;
  for (int j = jj; j <= i; j += 16) {
    float s = (__bfloat162float(acr[j]) + __bfloat162float(bdr[j])) * scale;
    float mn = fmaxf(m, s);
    l = l * __expf(m - mn) + __expf(s - mn);
    m = mn;
  }
  // merge the 4 lanes with same n within the wave (stride 16)
#pragma unroll
  for (int off = 16; off <= 32; off <<= 1) {
    float mo = __shfl_xor(m, off);
    float lo = __shfl_xor(l, off);
    float mn = fmaxf(m, mo);
    l = l * __expf(m - mn) + lo * __expf(mo - mn);
    m = mn;
  }
  __shared__ float sm[4][16], sl[4][16];
  int wave = tid >> 6, lane = tid & 63;
  if (lane < 16) { sm[wave][n] = m; sl[wave][n] = l; }
  __syncthreads();
  m = sm[0][n]; l = sl[0][n];
#pragma unroll
  for (int w = 1; w < 4; ++w) {
    float mo = sm[w][n], lo = sl[w][n];
    float mn = fmaxf(m, mo);
    l = l * __expf(m - mn) + lo * __expf(mo - mn);
    m = mn;
  }
  float rinv = 1.f / l;

  float* prow = probs + (long)i * T_SEQ * NHEAD;
  bf16* pbrow = pb + (long)n * T_SEQ * T_SEQ + (long)i * T_SEQ;
  for (int j = jj; j < T_SEQ; j += 16) {
    float p = 0.f;
    if (j <= i) {
      float s = (__bfloat162float(acr[j]) + __bfloat162float(bdr[j])) * scale;
      p = __expf(s - m) * rinv;
    }
    prow[j * NHEAD + n] = p;
    pbrow[j] = __float2bfloat16(p);
  }
}

// ---------------- host launch ----------------
extern "C" void kernel_launch(void* const* d_in, const int* in_sizes, int n_in,
                              void* d_out, int out_size, void* d_ws, size_t ws_size,
                              hipStream_t stream) {
  const float* input = (const float*)d_in[0];
  const float* pos   = (const float*)d_in[1];
  const float* rwb   = (const float*)d_in[2];
  const float* rrb   = (const float*)d_in[3];
  // d_in[4] = mask (causal, recomputed analytically)
  const float* ln1g  = (const float*)d_in[5];
  const float* ln1b  = (const float*)d_in[6];
  const float* qkvw  = (const float*)d_in[7];
  const float* rw    = (const float*)d_in[8];
  const float* ow    = (const float*)d_in[9];
  const float* ln2g  = (const float*)d_in[10];
  const float* ln2b  = (const float*)d_in[11];
  const float* ffw1  = (const float*)d_in[12];
  const float* ffb1  = (const float*)d_in[13];
  const float* ffw2  = (const float*)d_in[14];
  const float* ffb2  = (const float*)d_in[15];
  float* out = (float*)d_out;  // [0, 2M): x   [2M, 2M+67M): probs

  size_t off = 0;
  auto alloc = [&](size_t bytes) -> char* {
    char* p = (char*)d_ws + off;
    off += (bytes + 255) & ~(size_t)255;
    return p;
  };
  bf16* wqkvT = (bf16*)alloc(3072L * 1024 * 2);
  bf16* wrT   = (bf16*)alloc(1024L * 1024 * 2);
  bf16* woT   = (bf16*)alloc(1024L * 1024 * 2);
  bf16* wf1T  = (bf16*)alloc(4096L * 1024 * 2);
  bf16* wf2T  = (bf16*)alloc(1024L * 4096 * 2);
  bf16* qin   = (bf16*)alloc(2048L * 1024 * 2);
  bf16* posb  = (bf16*)alloc(2048L * 1024 * 2);
  bf16* Q1    = (bf16*)alloc(16L * 2048 * 64 * 2);
  bf16* Q2    = (bf16*)alloc(16L * 2048 * 64 * 2);
  bf16* Kb    = (bf16*)alloc(16L * 2048 * 64 * 2);
  bf16* Vt    = (bf16*)alloc(16L * 64 * 2048 * 2);
  bf16* Rk    = (bf16*)alloc(16L * 2048 * 64 * 2);
  bf16* ACb   = (bf16*)alloc(16L * 2048 * 2048 * 2);  // 134 MB
  bf16* BDb   = (bf16*)alloc(16L * 2048 * 2048 * 2);  // 134 MB
  bf16* pb    = (bf16*)alloc(16L * 2048 * 2048 * 2);  // 134 MB
  bf16* av    = (bf16*)alloc(2048L * 1024 * 2);
  float* xws  = (float*)alloc(2048L * 1024 * 4);
  bf16* yb    = (bf16*)alloc(2048L * 1024 * 2);
  bf16* hb    = (bf16*)alloc(2048L * 4096 * 2);

  dim3 tb(32, 8);
  transpose_cvt<<<dim3(3072 / 32, 1024 / 32), tb, 0, stream>>>(qkvw, wqkvT, 1024, 3072);
  transpose_cvt<<<dim3(1024 / 32, 1024 / 32), tb, 0, stream>>>(rw, wrT, 1024, 1024);
  transpose_cvt<<<dim3(1024 / 32, 1024 / 32), tb, 0, stream>>>(ow, woT, 1024, 1024);
  transpose_cvt<<<dim3(4096 / 32, 1024 / 32), tb, 0, stream>>>(ffw1, wf1T, 1024, 4096);
  transpose_cvt<<<dim3(1024 / 32, 4096 / 32), tb, 0, stream>>>(ffw2, wf2T, 4096, 1024);
  cvt_bf16<<<2048, 256, 0, stream>>>(pos, posb, 2048 * 1024 / 4);
  ln_cvt<<<2048, 256, 0, stream>>>(input, ln1g, ln1b, qin);

  {
    EpiQKV e{Q1, Q2, Kb, Vt, rwb, rrb};
    gemm_bt<128, EpiQKV><<<dim3(24, 16, 1), 256, 0, stream>>>(qin, wqkvT, 2048, 3072, 1024, 0, 0, e);
  }
  {
    EpiRk e{Rk};
    gemm_bt<128, EpiRk><<<dim3(8, 16, 1), 256, 0, stream>>>(posb, wrT, 2048, 1024, 1024, 0, 0, e);
  }
  {
    EpiAC e{ACb};
    gemm_bt<128, EpiAC><<<dim3(16, 16, 16), 256, 0, stream>>>(Q1, Kb, 2048, 2048, 64,
                                                              2048L * 64, 2048L * 64, e);
  }
  {
    EpiBD e{BDb};
    gemm_bt<128, EpiBD><<<dim3(16, 16, 16), 256, 0, stream>>>(Q2, Rk, 2048, 2048, 64,
                                                              2048L * 64, 2048L * 64, e);
  }
  softmax_k<<<2048, 256, 0, stream>>>(ACb, BDb, out + 2048L * 1024, pb);
  {
    EpiPV e{av};
    gemm_bt<64, EpiPV><<<dim3(1, 16, 16), 256, 0, stream>>>(pb, Vt, 2048, 64, 2048,
                                                            2048L * 2048, 64L * 2048, e);
  }
  {
    EpiO e{xws, input};
    gemm_bt<128, EpiO><<<dim3(8, 16, 1), 256, 0, stream>>>(av, woT, 2048, 1024, 1024, 0, 0, e);
  }
  ln_cvt<<<2048, 256, 0, stream>>>(xws, ln2g, ln2b, yb);
  {
    EpiFF1 e{hb, ffb1};
    gemm_bt<128, EpiFF1><<<dim3(32, 16, 1), 256, 0, stream>>>(yb, wf1T, 2048, 4096, 1024, 0, 0, e);
  }
  {
    EpiFF2 e{out, ffb2, xws};
    gemm_bt<128, EpiFF2><<<dim3(8, 16, 1), 256, 0, stream>>>(hb, wf2T, 2048, 1024, 4096, 0, 0, e);
  }
}

// Round 2
// 901.914 us; speedup vs baseline: 1.3224x; 1.3224x over previous
//
#include <hip/hip_runtime.h>
#include <hip/hip_bf16.h>
#include <stdint.h>

using bf16 = __hip_bfloat16;
using short8 = __attribute__((ext_vector_type(8))) short;   // 8 bf16 (4 VGPRs)
using f32x4 = __attribute__((ext_vector_type(4))) float;    // 4 fp32 acc

#define T_SEQ 2048
#define DMODEL 1024
#define NHEAD 16
#define DHEAD 64
#define DFF 4096

struct __align__(8) bf16x4 { bf16 x, y, z, w; };

__device__ __forceinline__ void async_cp16(const bf16* g, bf16* l) {
  __builtin_amdgcn_global_load_lds(
      (const __attribute__((address_space(1))) uint32_t*)g,
      (__attribute__((address_space(3))) uint32_t*)l, 16, 0, 0);
}

// ---------------- transpose + fp32->bf16 convert: src(R,C) -> dst(C,R) ----------------
__global__ __launch_bounds__(256) void transpose_cvt(const float* __restrict__ src,
                                                     bf16* __restrict__ dst,
                                                     int R, int C) {
  __shared__ float tile[32][33];
  int bx = blockIdx.x * 32;  // col of src
  int by = blockIdx.y * 32;  // row of src
  int tx = threadIdx.x, ty = threadIdx.y;  // 32 x 8
#pragma unroll
  for (int r = 0; r < 32; r += 8)
    tile[ty + r][tx] = src[(long)(by + ty + r) * C + bx + tx];
  __syncthreads();
#pragma unroll
  for (int r = 0; r < 32; r += 8)
    dst[(long)(bx + ty + r) * R + by + tx] = __float2bfloat16(tile[tx][ty + r]);
}

// ---------------- fp32 -> bf16 elementwise (x4) ----------------
__global__ __launch_bounds__(256) void cvt_bf16(const float* __restrict__ src,
                                                bf16* __restrict__ dst, int n4) {
  int idx = blockIdx.x * 256 + threadIdx.x;
  if (idx < n4) {
    float4 v = ((const float4*)src)[idx];
    bf16x4 o{__float2bfloat16(v.x), __float2bfloat16(v.y),
             __float2bfloat16(v.z), __float2bfloat16(v.w)};
    ((bf16x4*)dst)[idx] = o;
  }
}

// ---------------- LayerNorm (D=1024) -> bf16, one block per row ----------------
__global__ __launch_bounds__(256) void ln_cvt(const float* __restrict__ x,
                                              const float* __restrict__ g,
                                              const float* __restrict__ b,
                                              bf16* __restrict__ out) {
  int row = blockIdx.x;
  int tid = threadIdx.x;
  float4 v = ((const float4*)(x + (long)row * DMODEL))[tid];
  float s = v.x + v.y + v.z + v.w;
  float s2 = v.x * v.x + v.y * v.y + v.z * v.z + v.w * v.w;
#pragma unroll
  for (int off = 32; off > 0; off >>= 1) {
    s += __shfl_down(s, off);
    s2 += __shfl_down(s2, off);
  }
  __shared__ float ss[4], ss2[4];
  int wave = tid >> 6, lane = tid & 63;
  if (lane == 0) { ss[wave] = s; ss2[wave] = s2; }
  __syncthreads();
  s = ss[0] + ss[1] + ss[2] + ss[3];
  s2 = ss2[0] + ss2[1] + ss2[2] + ss2[3];
  float mean = s * (1.0f / DMODEL);
  float var = s2 * (1.0f / DMODEL) - mean * mean;
  float rstd = rsqrtf(var + 1e-5f);
  float4 gg = ((const float4*)g)[tid];
  float4 bb = ((const float4*)b)[tid];
  bf16x4 o{__float2bfloat16((v.x - mean) * rstd * gg.x + bb.x),
           __float2bfloat16((v.y - mean) * rstd * gg.y + bb.y),
           __float2bfloat16((v.z - mean) * rstd * gg.z + bb.z),
           __float2bfloat16((v.w - mean) * rstd * gg.w + bb.w)};
  ((bf16x4*)(out + (long)row * DMODEL))[tid] = o;
}

// ---------------- generic MFMA GEMM: C(M,N) = A(M,K) * Bt(N,K)^T ----------------
template <int BN, class Epi>
__global__ __launch_bounds__(256) void gemm_bt(const bf16* __restrict__ A,
                                               const bf16* __restrict__ Bt,
                                               int M, int N, int K,
                                               long aZstride, long bZstride, Epi epi) {
  constexpr int BM = 128;
  constexpr int BK = 32;
  constexpr int NT = BN / 32;
  __shared__ bf16 As[BM * BK];
  __shared__ bf16 Bs[BN * BK];

  const int bm = blockIdx.y, bn = blockIdx.x, z = blockIdx.z;
  if (epi.skip(bm, bn)) return;
  const bf16* Ab = A + (long)z * aZstride;
  const bf16* Bb = Bt + (long)z * bZstride;

  const int tid = threadIdx.x;
  const int lane = tid & 63;
  const int wave = tid >> 6;
  const int wr = wave >> 1;
  const int wc = wave & 1;
  const int kEnd = epi.kmax(bm, bn, K);

  const f32x4 zero4 = {0.f, 0.f, 0.f, 0.f};
  f32x4 acc[4][NT];
#pragma unroll
  for (int mt = 0; mt < 4; ++mt)
#pragma unroll
    for (int nt = 0; nt < NT; ++nt) acc[mt][nt] = zero4;

  const int sr = tid >> 2;         // staging row within 64-row round
  const int sc = (tid & 3) * 8;    // staging col
  const bf16* aG0 = Ab + (long)(bm * BM + sr) * K + sc;
  const bf16* aG1 = Ab + (long)(bm * BM + 64 + sr) * K + sc;
  bf16* aL0 = As + tid * 8;
  bf16* aL1 = As + 2048 + tid * 8;
  const bf16* bG0 = Bb + (long)(bn * BN + sr) * K + sc;
  bf16* bL0 = Bs + tid * 8;
  const bf16* bG1 = Bb + (long)(bn * BN + 64 + sr) * K + sc;  // BN==128 only
  bf16* bL1 = Bs + 2048 + tid * 8;

  const int aRow = wr * 64 + (lane & 15);
  const int bRow = wc * (BN / 2) + (lane & 15);
  const int kq = (lane >> 4) * 8;

  for (int k0 = 0; k0 < kEnd; k0 += BK) {
    __syncthreads();
    async_cp16(aG0, aL0);
    async_cp16(aG1, aL1);
    async_cp16(bG0, bL0);
    if constexpr (BN == 128) async_cp16(bG1, bL1);
    aG0 += BK; aG1 += BK; bG0 += BK;
    if constexpr (BN == 128) bG1 += BK;
    __syncthreads();
    short8 af[4], bfr[NT];
#pragma unroll
    for (int mt = 0; mt < 4; ++mt)
      af[mt] = *(const short8*)(As + (aRow + mt * 16) * BK + kq);
#pragma unroll
    for (int nt = 0; nt < NT; ++nt)
      bfr[nt] = *(const short8*)(Bs + (bRow + nt * 16) * BK + kq);
#pragma unroll
    for (int mt = 0; mt < 4; ++mt)
#pragma unroll
      for (int nt = 0; nt < NT; ++nt)
        acc[mt][nt] = __builtin_amdgcn_mfma_f32_16x16x32_bf16(af[mt], bfr[nt],
                                                              acc[mt][nt], 0, 0, 0);
  }

  const int rBase = (lane >> 4) * 4;
  const int cOff = lane & 15;
#pragma unroll
  for (int mt = 0; mt < 4; ++mt) {
#pragma unroll
    for (int nt = 0; nt < NT; ++nt) {
      int row = bm * BM + wr * 64 + mt * 16 + rBase;
      int col = bn * BN + wc * (BN / 2) + nt * 16 + cOff;
      f32x4 v = acc[mt][nt];
#pragma unroll
      for (int r = 0; r < 4; ++r) epi.store(z, row + r, col, v[r]);
    }
  }
}

// ---------------- epilogues ----------------
struct EpiQKV {
  bf16 *Q1, *Q2, *Kb, *Vt;
  const float *rwb, *rrb;
  __device__ bool skip(int, int) const { return false; }
  __device__ int kmax(int, int, int K) const { return K; }
  __device__ void store(int, int row, int col, float v) const {
    int n = (col >> 6) & 15, d = col & 63;
    long hoff = ((long)n * T_SEQ + row) * DHEAD + d;
    if (col < DMODEL) {
      Q1[hoff] = __float2bfloat16(v + rwb[col]);
      Q2[hoff] = __float2bfloat16(v + rrb[col]);
    } else if (col < 2 * DMODEL) {
      Kb[hoff] = __float2bfloat16(v);
    } else {
      Vt[((long)n * DHEAD + d) * T_SEQ + row] = __float2bfloat16(v);
    }
  }
};

struct EpiRk {
  bf16* Rk;
  __device__ bool skip(int, int) const { return false; }
  __device__ int kmax(int, int, int K) const { return K; }
  __device__ void store(int, int row, int col, float v) const {
    int n = col >> 6, d = col & 63;
    Rk[((long)n * T_SEQ + row) * DHEAD + d] = __float2bfloat16(v);
  }
};

struct EpiAC {
  bf16* out;
  __device__ bool skip(int bm, int bn) const { return bn > bm; }  // only j<=i needed
  __device__ int kmax(int, int, int K) const { return K; }
  __device__ void store(int z, int row, int col, float v) const {
    out[(long)z * T_SEQ * T_SEQ + (long)row * T_SEQ + col] = __float2bfloat16(v);
  }
};

// BD with rel-shift folded in: score[i][j] += bd  (j = col - (T-1) + row)
struct EpiBD {
  bf16* score;
  __device__ bool skip(int bm, int bn) const { return bm + bn < 15; }
  __device__ int kmax(int, int, int K) const { return K; }
  __device__ void store(int z, int row, int col, float v) const {
    int j = col - (T_SEQ - 1) + row;
    if (j >= 0) {
      long idx = (long)z * T_SEQ * T_SEQ + (long)row * T_SEQ + j;
      score[idx] = __float2bfloat16(__bfloat162float(score[idx]) + v);
    }
  }
};

struct EpiPV {
  bf16* av;
  __device__ bool skip(int, int) const { return false; }
  __device__ int kmax(int bm, int, int K) const {
    int kl = (bm + 1) * 128;
    return kl < K ? kl : K;
  }
  __device__ void store(int z, int row, int col, float v) const {
    av[(long)row * DMODEL + z * DHEAD + col] = __float2bfloat16(v);
  }
};

struct EpiO {
  float* xws;
  const float* inp;
  __device__ bool skip(int, int) const { return false; }
  __device__ int kmax(int, int, int K) const { return K; }
  __device__ void store(int, int row, int col, float v) const {
    long idx = (long)row * DMODEL + col;
    xws[idx] = v + inp[idx];
  }
};

struct EpiFF1 {
  bf16* h;
  const float* b1;
  __device__ bool skip(int, int) const { return false; }
  __device__ int kmax(int, int, int K) const { return K; }
  __device__ void store(int, int row, int col, float v) const {
    h[(long)row * DFF + col] = __float2bfloat16(fmaxf(v + b1[col], 0.f));
  }
};

struct EpiFF2 {
  float* out;
  const float* b2;
  const float* xws;
  __device__ bool skip(int, int) const { return false; }
  __device__ int kmax(int, int, int K) const { return K; }
  __device__ void store(int, int row, int col, float v) const {
    long idx = (long)row * DMODEL + col;
    out[idx] = v + b2[col] + xws[idx];
  }
};

// ---------------- softmax: block per row i; wave owns 4 heads end-to-end ----------------
// S[n][i][j] = (AC+BD) score (bf16, valid for j<=i). Writes probs fp32 [i][j][n]
// (coalesced via LDS transpose) and pb bf16 [n][i][j] (normalized, zeros up to
// round_up(i+1,128) which is all PV ever reads).
__global__ __launch_bounds__(256) void softmax_k(const bf16* __restrict__ S,
                                                 float* __restrict__ probs,
                                                 bf16* __restrict__ pb) {
  constexpr int HS = T_SEQ + 8;            // LDS head stride (bf16), 16B pad
  __shared__ bf16 pl[NHEAD * HS];          // ~65.8 KB
  __shared__ float rinv_s[NHEAD];
  const int i = blockIdx.x;
  const int tid = threadIdx.x;
  const int wave = tid >> 6, lane = tid & 63;
  const float scale = 0.125f;              // 1/sqrt(64)
  const int nch = ((i + 1) + 511) >> 9;    // 512-wide chunks covering the row

  for (int q = 0; q < 4; ++q) {
    const int h = wave * 4 + q;
    const bf16* row = S + (long)h * T_SEQ * T_SEQ + (long)i * T_SEQ;
    // pass 1: row max (vectorized, coalesced; masked tail)
    float m = -1e30f;
    for (int c = 0; c < nch; ++c) {
      int j0 = c * 512 + lane * 8;
      short8 v = *(const short8*)(row + j0);
#pragma unroll
      for (int e = 0; e < 8; ++e) {
        float s = (j0 + e <= i) ? __bfloat162float(((const bf16*)&v)[e]) * scale : -1e30f;
        m = fmaxf(m, s);
      }
    }
#pragma unroll
    for (int off = 1; off < 64; off <<= 1) m = fmaxf(m, __shfl_xor(m, off));
    // pass 2: exp (L1-resident re-read), accumulate l, stage unnormalized p in LDS
    float l = 0.f;
    for (int c = 0; c < nch; ++c) {
      int j0 = c * 512 + lane * 8;
      short8 v = *(const short8*)(row + j0);
      short8 o;
#pragma unroll
      for (int e = 0; e < 8; ++e) {
        float p = 0.f;
        if (j0 + e <= i) {
          p = __expf(__bfloat162float(((const bf16*)&v)[e]) * scale - m);
          l += p;
        }
        ((bf16*)&o)[e] = __float2bfloat16(p);
      }
      *(short8*)(pl + h * HS + j0) = o;
    }
#pragma unroll
    for (int off = 1; off < 64; off <<= 1) l += __shfl_xor(l, off);
    if (lane == 0) rinv_s[h] = 1.f / l;
  }
  __syncthreads();

  // phase C: probs fp32 [i][j][n] — float4 coalesced stores via LDS transpose
  float* prow = probs + (long)i * T_SEQ * NHEAD;
  const int n0 = (tid & 3) * 4;
  float rv0 = rinv_s[n0 + 0], rv1 = rinv_s[n0 + 1];
  float rv2 = rinv_s[n0 + 2], rv3 = rinv_s[n0 + 3];
  for (int it = 0; it < 32; ++it) {
    int o = tid * 4 + it * 1024;  // float index within row block (j*16+n)
    int j = o >> 4;
    float4 f = {0.f, 0.f, 0.f, 0.f};
    if (j <= i) {
      f.x = __bfloat162float(pl[(n0 + 0) * HS + j]) * rv0;
      f.y = __bfloat162float(pl[(n0 + 1) * HS + j]) * rv1;
      f.z = __bfloat162float(pl[(n0 + 2) * HS + j]) * rv2;
      f.w = __bfloat162float(pl[(n0 + 3) * HS + j]) * rv3;
    }
    ((float4*)prow)[tid + it * 256] = f;
  }

  // phase D: pb bf16 [n][i][j], normalized, j < round_up(i+1,128)
  const int kround = ((i >> 7) + 1) << 7;
  for (int q = 0; q < 4; ++q) {
    const int h = wave * 4 + q;
    bf16* prow_b = pb + (long)h * T_SEQ * T_SEQ + (long)i * T_SEQ;
    float rinv = rinv_s[h];
    for (int j0 = lane * 8; j0 < kround; j0 += 512) {
      short8 v = *(const short8*)(pl + h * HS + j0);
      short8 o;
#pragma unroll
      for (int e = 0; e < 8; ++e)
        ((bf16*)&o)[e] = __float2bfloat16(__bfloat162float(((const bf16*)&v)[e]) * rinv);
      *(short8*)(prow_b + j0) = o;
    }
  }
}

// ---------------- host launch ----------------
extern "C" void kernel_launch(void* const* d_in, const int* in_sizes, int n_in,
                              void* d_out, int out_size, void* d_ws, size_t ws_size,
                              hipStream_t stream) {
  const float* input = (const float*)d_in[0];
  const float* pos   = (const float*)d_in[1];
  const float* rwb   = (const float*)d_in[2];
  const float* rrb   = (const float*)d_in[3];
  // d_in[4] = mask (causal, recomputed analytically)
  const float* ln1g  = (const float*)d_in[5];
  const float* ln1b  = (const float*)d_in[6];
  const float* qkvw  = (const float*)d_in[7];
  const float* rw    = (const float*)d_in[8];
  const float* ow    = (const float*)d_in[9];
  const float* ln2g  = (const float*)d_in[10];
  const float* ln2b  = (const float*)d_in[11];
  const float* ffw1  = (const float*)d_in[12];
  const float* ffb1  = (const float*)d_in[13];
  const float* ffw2  = (const float*)d_in[14];
  const float* ffb2  = (const float*)d_in[15];
  float* out = (float*)d_out;  // [0, 2M): x   [2M, 2M+67M): probs

  size_t off = 0;
  auto alloc = [&](size_t bytes) -> char* {
    char* p = (char*)d_ws + off;
    off += (bytes + 255) & ~(size_t)255;
    return p;
  };
  bf16* wqkvT = (bf16*)alloc(3072L * 1024 * 2);
  bf16* wrT   = (bf16*)alloc(1024L * 1024 * 2);
  bf16* woT   = (bf16*)alloc(1024L * 1024 * 2);
  bf16* wf1T  = (bf16*)alloc(4096L * 1024 * 2);
  bf16* wf2T  = (bf16*)alloc(1024L * 4096 * 2);
  bf16* qin   = (bf16*)alloc(2048L * 1024 * 2);
  bf16* posb  = (bf16*)alloc(2048L * 1024 * 2);
  bf16* Q1    = (bf16*)alloc(16L * 2048 * 64 * 2);
  bf16* Q2    = (bf16*)alloc(16L * 2048 * 64 * 2);
  bf16* Kb    = (bf16*)alloc(16L * 2048 * 64 * 2);
  bf16* Vt    = (bf16*)alloc(16L * 64 * 2048 * 2);
  bf16* Rk    = (bf16*)alloc(16L * 2048 * 64 * 2);
  bf16* ACb   = (bf16*)alloc(16L * 2048 * 2048 * 2);  // 134 MB score (AC += BD)
  bf16* pb    = (bf16*)alloc(16L * 2048 * 2048 * 2);  // 134 MB probs bf16
  bf16* av    = (bf16*)alloc(2048L * 1024 * 2);
  float* xws  = (float*)alloc(2048L * 1024 * 4);
  bf16* yb    = (bf16*)alloc(2048L * 1024 * 2);
  bf16* hb    = (bf16*)alloc(2048L * 4096 * 2);

  dim3 tb(32, 8);
  transpose_cvt<<<dim3(3072 / 32, 1024 / 32), tb, 0, stream>>>(qkvw, wqkvT, 1024, 3072);
  transpose_cvt<<<dim3(1024 / 32, 1024 / 32), tb, 0, stream>>>(rw, wrT, 1024, 1024);
  transpose_cvt<<<dim3(1024 / 32, 1024 / 32), tb, 0, stream>>>(ow, woT, 1024, 1024);
  transpose_cvt<<<dim3(4096 / 32, 1024 / 32), tb, 0, stream>>>(ffw1, wf1T, 1024, 4096);
  transpose_cvt<<<dim3(1024 / 32, 4096 / 32), tb, 0, stream>>>(ffw2, wf2T, 4096, 1024);
  cvt_bf16<<<2048, 256, 0, stream>>>(pos, posb, 2048 * 1024 / 4);
  ln_cvt<<<2048, 256, 0, stream>>>(input, ln1g, ln1b, qin);

  {
    EpiQKV e{Q1, Q2, Kb, Vt, rwb, rrb};
    gemm_bt<128, EpiQKV><<<dim3(24, 16, 1), 256, 0, stream>>>(qin, wqkvT, 2048, 3072, 1024, 0, 0, e);
  }
  {
    EpiRk e{Rk};
    gemm_bt<128, EpiRk><<<dim3(8, 16, 1), 256, 0, stream>>>(posb, wrT, 2048, 1024, 1024, 0, 0, e);
  }
  {
    EpiAC e{ACb};
    gemm_bt<128, EpiAC><<<dim3(16, 16, 16), 256, 0, stream>>>(Q1, Kb, 2048, 2048, 64,
                                                              2048L * 64, 2048L * 64, e);
  }
  {
    EpiBD e{ACb};  // RMW: score += rel-shifted BD
    gemm_bt<128, EpiBD><<<dim3(16, 16, 16), 256, 0, stream>>>(Q2, Rk, 2048, 2048, 64,
                                                              2048L * 64, 2048L * 64, e);
  }
  softmax_k<<<2048, 256, 0, stream>>>(ACb, out + 2048L * 1024, pb);
  {
    EpiPV e{av};
    gemm_bt<64, EpiPV><<<dim3(1, 16, 16), 256, 0, stream>>>(pb, Vt, 2048, 64, 2048,
                                                            2048L * 2048, 64L * 2048, e);
  }
  {
    EpiO e{xws, input};
    gemm_bt<128, EpiO><<<dim3(8, 16, 1), 256, 0, stream>>>(av, woT, 2048, 1024, 1024, 0, 0, e);
  }
  ln_cvt<<<2048, 256, 0, stream>>>(xws, ln2g, ln2b, yb);
  {
    EpiFF1 e{hb, ffb1};
    gemm_bt<128, EpiFF1><<<dim3(32, 16, 1), 256, 0, stream>>>(yb, wf1T, 2048, 4096, 1024, 0, 0, e);
  }
  {
    EpiFF2 e{out, ffb2, xws};
    gemm_bt<128, EpiFF2><<<dim3(8, 16, 1), 256, 0, stream>>>(hb, wf2T, 2048, 1024, 4096, 0, 0, e);
  }
}

// Round 3
// 895.307 us; speedup vs baseline: 1.3321x; 1.0074x over previous
//
#include <hip/hip_runtime.h>
#include <hip/hip_bf16.h>
#include <stdint.h>

using bf16 = __hip_bfloat16;
using short8 = __attribute__((ext_vector_type(8))) short;   // 8 bf16 (4 VGPRs)
using f32x4 = __attribute__((ext_vector_type(4))) float;    // 4 fp32 acc

#define T_SEQ 2048
#define DMODEL 1024
#define NHEAD 16
#define DHEAD 64
#define DFF 4096

struct __align__(8) bf16x4 { bf16 x, y, z, w; };

__device__ __forceinline__ void async_cp16(const bf16* g, bf16* l) {
  __builtin_amdgcn_global_load_lds(
      (const __attribute__((address_space(1))) uint32_t*)g,
      (__attribute__((address_space(3))) uint32_t*)l, 16, 0, 0);
}

// ---------------- transpose + fp32->bf16 convert: src(R,C) -> dst(C,R) ----------------
__global__ __launch_bounds__(256) void transpose_cvt(const float* __restrict__ src,
                                                     bf16* __restrict__ dst,
                                                     int R, int C) {
  __shared__ float tile[32][33];
  int bx = blockIdx.x * 32;  // col of src
  int by = blockIdx.y * 32;  // row of src
  int tx = threadIdx.x, ty = threadIdx.y;  // 32 x 8
#pragma unroll
  for (int r = 0; r < 32; r += 8)
    tile[ty + r][tx] = src[(long)(by + ty + r) * C + bx + tx];
  __syncthreads();
#pragma unroll
  for (int r = 0; r < 32; r += 8)
    dst[(long)(bx + ty + r) * R + by + tx] = __float2bfloat16(tile[tx][ty + r]);
}

// ---------------- fp32 -> bf16 elementwise (x4) ----------------
__global__ __launch_bounds__(256) void cvt_bf16(const float* __restrict__ src,
                                                bf16* __restrict__ dst, int n4) {
  int idx = blockIdx.x * 256 + threadIdx.x;
  if (idx < n4) {
    float4 v = ((const float4*)src)[idx];
    bf16x4 o{__float2bfloat16(v.x), __float2bfloat16(v.y),
             __float2bfloat16(v.z), __float2bfloat16(v.w)};
    ((bf16x4*)dst)[idx] = o;
  }
}

// ---------------- LayerNorm (D=1024) -> bf16, one block per row ----------------
__global__ __launch_bounds__(256) void ln_cvt(const float* __restrict__ x,
                                              const float* __restrict__ g,
                                              const float* __restrict__ b,
                                              bf16* __restrict__ out) {
  int row = blockIdx.x;
  int tid = threadIdx.x;
  float4 v = ((const float4*)(x + (long)row * DMODEL))[tid];
  float s = v.x + v.y + v.z + v.w;
  float s2 = v.x * v.x + v.y * v.y + v.z * v.z + v.w * v.w;
#pragma unroll
  for (int off = 32; off > 0; off >>= 1) {
    s += __shfl_down(s, off);
    s2 += __shfl_down(s2, off);
  }
  __shared__ float ss[4], ss2[4];
  int wave = tid >> 6, lane = tid & 63;
  if (lane == 0) { ss[wave] = s; ss2[wave] = s2; }
  __syncthreads();
  s = ss[0] + ss[1] + ss[2] + ss[3];
  s2 = ss2[0] + ss2[1] + ss2[2] + ss2[3];
  float mean = s * (1.0f / DMODEL);
  float var = s2 * (1.0f / DMODEL) - mean * mean;
  float rstd = rsqrtf(var + 1e-5f);
  float4 gg = ((const float4*)g)[tid];
  float4 bb = ((const float4*)b)[tid];
  bf16x4 o{__float2bfloat16((v.x - mean) * rstd * gg.x + bb.x),
           __float2bfloat16((v.y - mean) * rstd * gg.y + bb.y),
           __float2bfloat16((v.z - mean) * rstd * gg.z + bb.z),
           __float2bfloat16((v.w - mean) * rstd * gg.w + bb.w)};
  ((bf16x4*)(out + (long)row * DMODEL))[tid] = o;
}

// ---------------- generic MFMA GEMM: C(M,N) = A(M,K) * Bt(N,K)^T ----------------
template <int BN, class Epi>
__global__ __launch_bounds__(256) void gemm_bt(const bf16* __restrict__ A,
                                               const bf16* __restrict__ Bt,
                                               int M, int N, int K,
                                               long aZstride, long bZstride, Epi epi) {
  constexpr int BM = 128;
  constexpr int BK = 32;
  constexpr int NT = BN / 32;
  __shared__ bf16 As[BM * BK];
  __shared__ bf16 Bs[BN * BK];

  const int bm = blockIdx.y, bn = blockIdx.x, z = blockIdx.z;
  const bf16* Ab = A + (long)z * aZstride;
  const bf16* Bb = Bt + (long)z * bZstride;

  const int tid = threadIdx.x;
  const int lane = tid & 63;
  const int wave = tid >> 6;
  const int wr = wave >> 1;
  const int wc = wave & 1;
  const int kEnd = epi.kmax(bm, bn, K);

  const f32x4 zero4 = {0.f, 0.f, 0.f, 0.f};
  f32x4 acc[4][NT];
#pragma unroll
  for (int mt = 0; mt < 4; ++mt)
#pragma unroll
    for (int nt = 0; nt < NT; ++nt) acc[mt][nt] = zero4;

  const int sr = tid >> 2;         // staging row within 64-row round
  const int sc = (tid & 3) * 8;    // staging col
  const bf16* aG0 = Ab + (long)(bm * BM + sr) * K + sc;
  const bf16* aG1 = Ab + (long)(bm * BM + 64 + sr) * K + sc;
  bf16* aL0 = As + tid * 8;
  bf16* aL1 = As + 2048 + tid * 8;
  const bf16* bG0 = Bb + (long)(bn * BN + sr) * K + sc;
  bf16* bL0 = Bs + tid * 8;
  const bf16* bG1 = Bb + (long)(bn * BN + 64 + sr) * K + sc;  // BN==128 only
  bf16* bL1 = Bs + 2048 + tid * 8;

  const int aRow = wr * 64 + (lane & 15);
  const int bRow = wc * (BN / 2) + (lane & 15);
  const int kq = (lane >> 4) * 8;

  for (int k0 = 0; k0 < kEnd; k0 += BK) {
    __syncthreads();
    async_cp16(aG0, aL0);
    async_cp16(aG1, aL1);
    async_cp16(bG0, bL0);
    if constexpr (BN == 128) async_cp16(bG1, bL1);
    aG0 += BK; aG1 += BK; bG0 += BK;
    if constexpr (BN == 128) bG1 += BK;
    __syncthreads();
    short8 af[4], bfr[NT];
#pragma unroll
    for (int mt = 0; mt < 4; ++mt)
      af[mt] = *(const short8*)(As + (aRow + mt * 16) * BK + kq);
#pragma unroll
    for (int nt = 0; nt < NT; ++nt)
      bfr[nt] = *(const short8*)(Bs + (bRow + nt * 16) * BK + kq);
#pragma unroll
    for (int mt = 0; mt < 4; ++mt)
#pragma unroll
      for (int nt = 0; nt < NT; ++nt)
        acc[mt][nt] = __builtin_amdgcn_mfma_f32_16x16x32_bf16(af[mt], bfr[nt],
                                                              acc[mt][nt], 0, 0, 0);
  }

  const int rBase = (lane >> 4) * 4;
  const int cOff = lane & 15;
#pragma unroll
  for (int mt = 0; mt < 4; ++mt) {
#pragma unroll
    for (int nt = 0; nt < NT; ++nt) {
      int row = bm * BM + wr * 64 + mt * 16 + rBase;
      int col = bn * BN + wc * (BN / 2) + nt * 16 + cOff;
      f32x4 v = acc[mt][nt];
#pragma unroll
      for (int r = 0; r < 4; ++r) epi.store(z, row + r, col, v[r]);
    }
  }
}

// ---------------- epilogues ----------------
struct EpiQKV {
  bf16 *Qh, *Kb, *Vt;
  __device__ int kmax(int, int, int K) const { return K; }
  __device__ void store(int, int row, int col, float v) const {
    int n = (col >> 6) & 15, d = col & 63;
    long hoff = ((long)n * T_SEQ + row) * DHEAD + d;
    if (col < DMODEL) {
      Qh[hoff] = __float2bfloat16(v);
    } else if (col < 2 * DMODEL) {
      Kb[hoff] = __float2bfloat16(v);
    } else {
      Vt[((long)n * DHEAD + d) * T_SEQ + row] = __float2bfloat16(v);
    }
  }
};

struct EpiRk {
  bf16* Rk;
  __device__ int kmax(int, int, int K) const { return K; }
  __device__ void store(int, int row, int col, float v) const {
    int n = col >> 6, d = col & 63;
    Rk[((long)n * T_SEQ + row) * DHEAD + d] = __float2bfloat16(v);
  }
};

struct EpiPV {
  bf16* av;
  __device__ int kmax(int bm, int, int K) const {
    int kl = (bm + 1) * 128;
    return kl < K ? kl : K;
  }
  __device__ void store(int z, int row, int col, float v) const {
    av[(long)row * DMODEL + z * DHEAD + col] = __float2bfloat16(v);
  }
};

struct EpiO {
  float* xws;
  const float* inp;
  __device__ int kmax(int, int, int K) const { return K; }
  __device__ void store(int, int row, int col, float v) const {
    long idx = (long)row * DMODEL + col;
    xws[idx] = v + inp[idx];
  }
};

struct EpiFF1 {
  bf16* h;
  const float* b1;
  __device__ int kmax(int, int, int K) const { return K; }
  __device__ void store(int, int row, int col, float v) const {
    h[(long)row * DFF + col] = __float2bfloat16(fmaxf(v + b1[col], 0.f));
  }
};

struct EpiFF2 {
  float* out;
  const float* b2;
  const float* xws;
  __device__ int kmax(int, int, int K) const { return K; }
  __device__ void store(int, int row, int col, float v) const {
    long idx = (long)row * DMODEL + col;
    out[idx] = v + b2[col] + xws[idx];
  }
};

// ---------------- rank-1 bias rows: acB[n][j] = rwb_n . K[n][j],  rrbR[n][u] = rrb_n . Rk[n][u]
__global__ __launch_bounds__(256) void bias_k(const bf16* __restrict__ Kb,
                                              const bf16* __restrict__ Rk,
                                              const float* __restrict__ rwb,
                                              const float* __restrict__ rrb,
                                              float* __restrict__ acB,
                                              float* __restrict__ rrbR) {
  int idx = blockIdx.x * 256 + threadIdx.x;   // 16*2048
  int n = idx >> 11;
  const short8* kp = (const short8*)(Kb + (long)idx * DHEAD);
  const short8* rp = (const short8*)(Rk + (long)idx * DHEAD);
  float s1 = 0.f, s2 = 0.f;
#pragma unroll
  for (int q8 = 0; q8 < 8; ++q8) {
    short8 kv = kp[q8], rv = rp[q8];
#pragma unroll
    for (int e = 0; e < 8; ++e) {
      float w1 = rwb[n * DHEAD + q8 * 8 + e];
      float w2 = rrb[n * DHEAD + q8 * 8 + e];
      s1 += w1 * __bfloat162float(((const bf16*)&kv)[e]);
      s2 += w2 * __bfloat162float(((const bf16*)&rv)[e]);
    }
  }
  acB[idx] = s1;
  rrbR[idx] = s2;
}

// ---------------- fused score kernel: score = Q.K^T + rwb-term + relshift(Q.Rk^T) + rrb-term
// Tile (bm,bn) 128x128, head z. BD[i,j] = Q[i].Rk[j-i+2047]; band u = c-r+128,
// g = base+u, base = 128*(bn-bm)+2047-128. W(128x256)=Q.Band^T via MFMA; W routed
// through a 64-row LDS half-tile (2 rounds) to apply the per-element diagonal shift.
__global__ __launch_bounds__(256) void score_k(const bf16* __restrict__ Qh,
                                               const bf16* __restrict__ Kb,
                                               const bf16* __restrict__ Rk,
                                               const float* __restrict__ acB,
                                               const float* __restrict__ rrbR,
                                               bf16* __restrict__ score) {
  const int bn = blockIdx.x, bm = blockIdx.y, z = blockIdx.z;
  if (bn > bm) return;
  __shared__ char smem[65536];
  bf16* Qs  = (bf16*)smem;             // 128x64, two 32-wide K panels (16 KB)
  bf16* Ks  = (bf16*)(smem + 16384);   // 128x64 (16 KB)
  bf16* Bnd = (bf16*)(smem + 32768);   // 256x64 (32 KB)

  const int tid = threadIdx.x;
  const int lane = tid & 63, wave = tid >> 6;
  const int wr = wave >> 1, wc = wave & 1;
  const int kq = (lane >> 4) * 8;
  const int l15 = lane & 15;
  const int base = 128 * (bn - bm) + T_SEQ - 1 - 128;

  const bf16* Qg = Qh + ((long)z * T_SEQ + bm * 128) * DHEAD;
  const bf16* Kg = Kb + ((long)z * T_SEQ + bn * 128) * DHEAD;
  const bf16* Rg = Rk + (long)z * T_SEQ * DHEAD;

  // stage Q,K (panels: kh*4096 + r*32 + c elements)
#pragma unroll
  for (int it = 0; it < 4; ++it) {
    int s = it * 256 + tid;
    int kh = s >> 9, r = (s >> 2) & 127, c = (s & 3) * 8;
    async_cp16(Qg + (long)r * DHEAD + kh * 32 + c, Qs + s * 8);
    async_cp16(Kg + (long)r * DHEAD + kh * 32 + c, Ks + s * 8);
  }
  // stage Rk band (panels: kh*8192 + u*32 + c elements), clamped rows
#pragma unroll
  for (int it = 0; it < 8; ++it) {
    int s = it * 256 + tid;
    int kh = s >> 10, u = (s >> 2) & 255, c = (s & 3) * 8;
    int g = base + u;
    g = g < 0 ? 0 : (g > T_SEQ - 1 ? T_SEQ - 1 : g);
    async_cp16(Rg + (long)g * DHEAD + kh * 32 + c, Bnd + s * 8);
  }

  const f32x4 zero4 = {0.f, 0.f, 0.f, 0.f};
  f32x4 accA[4][4], accW[4][8];
#pragma unroll
  for (int mt = 0; mt < 4; ++mt) {
#pragma unroll
    for (int nt = 0; nt < 4; ++nt) accA[mt][nt] = zero4;
#pragma unroll
    for (int ut = 0; ut < 8; ++ut) accW[mt][ut] = zero4;
  }

  __syncthreads();
#pragma unroll
  for (int kh = 0; kh < 2; ++kh) {
    short8 qa[4], kf[4], wf[8];
#pragma unroll
    for (int mt = 0; mt < 4; ++mt)
      qa[mt] = *(const short8*)(Qs + kh * 4096 + (wr * 64 + mt * 16 + l15) * 32 + kq);
#pragma unroll
    for (int nt = 0; nt < 4; ++nt)
      kf[nt] = *(const short8*)(Ks + kh * 4096 + (wc * 64 + nt * 16 + l15) * 32 + kq);
#pragma unroll
    for (int ut = 0; ut < 8; ++ut)
      wf[ut] = *(const short8*)(Bnd + kh * 8192 + (wc * 128 + ut * 16 + l15) * 32 + kq);
#pragma unroll
    for (int mt = 0; mt < 4; ++mt) {
#pragma unroll
      for (int nt = 0; nt < 4; ++nt)
        accA[mt][nt] = __builtin_amdgcn_mfma_f32_16x16x32_bf16(qa[mt], kf[nt], accA[mt][nt], 0, 0, 0);
#pragma unroll
      for (int ut = 0; ut < 8; ++ut)
        accW[mt][ut] = __builtin_amdgcn_mfma_f32_16x16x32_bf16(qa[mt], wf[ut], accW[mt][ut], 0, 0, 0);
    }
  }
  __syncthreads();  // all frag reads done; smem reusable

  // per-lane bias terms (L1-resident rows)
  float wbias[8];
#pragma unroll
  for (int ut = 0; ut < 8; ++ut) {
    int u = wc * 128 + ut * 16 + l15;
    int g = base + u;
    g = g < 0 ? 0 : (g > T_SEQ - 1 ? T_SEQ - 1 : g);
    wbias[ut] = rrbR[(long)z * T_SEQ + g];
  }
  float abias[4];
#pragma unroll
  for (int nt = 0; nt < 4; ++nt)
    abias[nt] = acB[(long)z * T_SEQ + bn * 128 + wc * 64 + nt * 16 + l15];

  bf16* WlH = (bf16*)smem;  // 64 x 272 bf16 half-tile (34816 B)
  const int quad4 = (lane >> 4) * 4;
  bf16* srow = score + (long)z * T_SEQ * T_SEQ;

  for (int half = 0; half < 2; ++half) {
    if (wr == half) {
#pragma unroll
      for (int mt = 0; mt < 4; ++mt)
#pragma unroll
        for (int ut = 0; ut < 8; ++ut) {
          int lr = mt * 16 + quad4;
          int u = wc * 128 + ut * 16 + l15;
#pragma unroll
          for (int reg = 0; reg < 4; ++reg)
            WlH[(lr + reg) * 272 + u] = __float2bfloat16(accW[mt][ut][reg] + wbias[ut]);
        }
    }
    __syncthreads();
    if (wr == half) {
#pragma unroll
      for (int mt = 0; mt < 4; ++mt)
#pragma unroll
        for (int nt = 0; nt < 4; ++nt) {
          int lr = mt * 16 + quad4;
          int c = wc * 64 + nt * 16 + l15;
#pragma unroll
          for (int reg = 0; reg < 4; ++reg) {
            int r = half * 64 + lr + reg;
            int u = c - r + 128;
            float v = accA[mt][nt][reg] + abias[nt] +
                      __bfloat162float(WlH[(lr + reg) * 272 + u]);
            srow[(long)(bm * 128 + r) * T_SEQ + bn * 128 + c] = __float2bfloat16(v);
          }
        }
    }
    __syncthreads();
  }
}

// ---------------- softmax: block per row i; wave owns 4 heads end-to-end ----------------
__global__ __launch_bounds__(256) void softmax_k(const bf16* __restrict__ S,
                                                 float* __restrict__ probs,
                                                 bf16* __restrict__ pb) {
  constexpr int HS = T_SEQ + 8;            // LDS head stride (bf16), 16B pad
  __shared__ bf16 pl[NHEAD * HS];          // ~65.8 KB
  __shared__ float rinv_s[NHEAD];
  const int i = blockIdx.x;
  const int tid = threadIdx.x;
  const int wave = tid >> 6, lane = tid & 63;
  const float scale = 0.125f;              // 1/sqrt(64)
  const int nch = ((i + 1) + 511) >> 9;    // 512-wide chunks covering the row

  for (int q = 0; q < 4; ++q) {
    const int h = wave * 4 + q;
    const bf16* row = S + (long)h * T_SEQ * T_SEQ + (long)i * T_SEQ;
    float m = -1e30f;
    for (int c = 0; c < nch; ++c) {
      int j0 = c * 512 + lane * 8;
      short8 v = *(const short8*)(row + j0);
#pragma unroll
      for (int e = 0; e < 8; ++e) {
        float s = (j0 + e <= i) ? __bfloat162float(((const bf16*)&v)[e]) * scale : -1e30f;
        m = fmaxf(m, s);
      }
    }
#pragma unroll
    for (int off = 1; off < 64; off <<= 1) m = fmaxf(m, __shfl_xor(m, off));
    float l = 0.f;
    for (int c = 0; c < nch; ++c) {
      int j0 = c * 512 + lane * 8;
      short8 v = *(const short8*)(row + j0);
      short8 o;
#pragma unroll
      for (int e = 0; e < 8; ++e) {
        float p = 0.f;
        if (j0 + e <= i) {
          p = __expf(__bfloat162float(((const bf16*)&v)[e]) * scale - m);
          l += p;
        }
        ((bf16*)&o)[e] = __float2bfloat16(p);
      }
      *(short8*)(pl + h * HS + j0) = o;
    }
#pragma unroll
    for (int off = 1; off < 64; off <<= 1) l += __shfl_xor(l, off);
    if (lane == 0) rinv_s[h] = 1.f / l;
  }
  __syncthreads();

  // probs fp32 [i][j][n] — float4 coalesced via LDS transpose
  float* prow = probs + (long)i * T_SEQ * NHEAD;
  const int n0 = (tid & 3) * 4;
  float rv0 = rinv_s[n0 + 0], rv1 = rinv_s[n0 + 1];
  float rv2 = rinv_s[n0 + 2], rv3 = rinv_s[n0 + 3];
  for (int it = 0; it < 32; ++it) {
    int o = tid * 4 + it * 1024;
    int j = o >> 4;
    float4 f = {0.f, 0.f, 0.f, 0.f};
    if (j <= i) {
      f.x = __bfloat162float(pl[(n0 + 0) * HS + j]) * rv0;
      f.y = __bfloat162float(pl[(n0 + 1) * HS + j]) * rv1;
      f.z = __bfloat162float(pl[(n0 + 2) * HS + j]) * rv2;
      f.w = __bfloat162float(pl[(n0 + 3) * HS + j]) * rv3;
    }
    ((float4*)prow)[tid + it * 256] = f;
  }

  // pb bf16 [n][i][j], normalized, j < round_up(i+1,128)
  const int kround = ((i >> 7) + 1) << 7;
  for (int q = 0; q < 4; ++q) {
    const int h = wave * 4 + q;
    bf16* prow_b = pb + (long)h * T_SEQ * T_SEQ + (long)i * T_SEQ;
    float rinv = rinv_s[h];
    for (int j0 = lane * 8; j0 < kround; j0 += 512) {
      short8 v = *(const short8*)(pl + h * HS + j0);
      short8 o;
#pragma unroll
      for (int e = 0; e < 8; ++e)
        ((bf16*)&o)[e] = __float2bfloat16(__bfloat162float(((const bf16*)&v)[e]) * rinv);
      *(short8*)(prow_b + j0) = o;
    }
  }
}

// ---------------- host launch ----------------
extern "C" void kernel_launch(void* const* d_in, const int* in_sizes, int n_in,
                              void* d_out, int out_size, void* d_ws, size_t ws_size,
                              hipStream_t stream) {
  const float* input = (const float*)d_in[0];
  const float* pos   = (const float*)d_in[1];
  const float* rwb   = (const float*)d_in[2];
  const float* rrb   = (const float*)d_in[3];
  // d_in[4] = mask (causal, recomputed analytically)
  const float* ln1g  = (const float*)d_in[5];
  const float* ln1b  = (const float*)d_in[6];
  const float* qkvw  = (const float*)d_in[7];
  const float* rw    = (const float*)d_in[8];
  const float* ow    = (const float*)d_in[9];
  const float* ln2g  = (const float*)d_in[10];
  const float* ln2b  = (const float*)d_in[11];
  const float* ffw1  = (const float*)d_in[12];
  const float* ffb1  = (const float*)d_in[13];
  const float* ffw2  = (const float*)d_in[14];
  const float* ffb2  = (const float*)d_in[15];
  float* out = (float*)d_out;  // [0, 2M): x   [2M, 2M+67M): probs

  size_t off = 0;
  auto alloc = [&](size_t bytes) -> char* {
    char* p = (char*)d_ws + off;
    off += (bytes + 255) & ~(size_t)255;
    return p;
  };
  bf16* wqkvT = (bf16*)alloc(3072L * 1024 * 2);
  bf16* wrT   = (bf16*)alloc(1024L * 1024 * 2);
  bf16* woT   = (bf16*)alloc(1024L * 1024 * 2);
  bf16* wf1T  = (bf16*)alloc(4096L * 1024 * 2);
  bf16* wf2T  = (bf16*)alloc(1024L * 4096 * 2);
  bf16* qin   = (bf16*)alloc(2048L * 1024 * 2);
  bf16* posb  = (bf16*)alloc(2048L * 1024 * 2);
  bf16* Qh    = (bf16*)alloc(16L * 2048 * 64 * 2);
  bf16* Kb    = (bf16*)alloc(16L * 2048 * 64 * 2);
  bf16* Vt    = (bf16*)alloc(16L * 64 * 2048 * 2);
  bf16* Rk    = (bf16*)alloc(16L * 2048 * 64 * 2);
  float* acB  = (float*)alloc(16L * 2048 * 4);
  float* rrbR = (float*)alloc(16L * 2048 * 4);
  bf16* ACb   = (bf16*)alloc(16L * 2048 * 2048 * 2);  // 134 MB score
  bf16* pb    = (bf16*)alloc(16L * 2048 * 2048 * 2);  // 134 MB probs bf16
  bf16* av    = (bf16*)alloc(2048L * 1024 * 2);
  float* xws  = (float*)alloc(2048L * 1024 * 4);
  bf16* yb    = (bf16*)alloc(2048L * 1024 * 2);
  bf16* hb    = (bf16*)alloc(2048L * 4096 * 2);

  dim3 tb(32, 8);
  transpose_cvt<<<dim3(3072 / 32, 1024 / 32), tb, 0, stream>>>(qkvw, wqkvT, 1024, 3072);
  transpose_cvt<<<dim3(1024 / 32, 1024 / 32), tb, 0, stream>>>(rw, wrT, 1024, 1024);
  transpose_cvt<<<dim3(1024 / 32, 1024 / 32), tb, 0, stream>>>(ow, woT, 1024, 1024);
  transpose_cvt<<<dim3(4096 / 32, 1024 / 32), tb, 0, stream>>>(ffw1, wf1T, 1024, 4096);
  transpose_cvt<<<dim3(1024 / 32, 4096 / 32), tb, 0, stream>>>(ffw2, wf2T, 4096, 1024);
  cvt_bf16<<<2048, 256, 0, stream>>>(pos, posb, 2048 * 1024 / 4);
  ln_cvt<<<2048, 256, 0, stream>>>(input, ln1g, ln1b, qin);

  {
    EpiQKV e{Qh, Kb, Vt};
    gemm_bt<128, EpiQKV><<<dim3(24, 16, 1), 256, 0, stream>>>(qin, wqkvT, 2048, 3072, 1024, 0, 0, e);
  }
  {
    EpiRk e{Rk};
    gemm_bt<128, EpiRk><<<dim3(8, 16, 1), 256, 0, stream>>>(posb, wrT, 2048, 1024, 1024, 0, 0, e);
  }
  bias_k<<<128, 256, 0, stream>>>(Kb, Rk, rwb, rrb, acB, rrbR);
  score_k<<<dim3(16, 16, 16), 256, 0, stream>>>(Qh, Kb, Rk, acB, rrbR, ACb);
  softmax_k<<<2048, 256, 0, stream>>>(ACb, out + 2048L * 1024, pb);
  {
    EpiPV e{av};
    gemm_bt<64, EpiPV><<<dim3(1, 16, 16), 256, 0, stream>>>(pb, Vt, 2048, 64, 2048,
                                                            2048L * 2048, 64L * 2048, e);
  }
  {
    EpiO e{xws, input};
    gemm_bt<128, EpiO><<<dim3(8, 16, 1), 256, 0, stream>>>(av, woT, 2048, 1024, 1024, 0, 0, e);
  }
  ln_cvt<<<2048, 256, 0, stream>>>(xws, ln2g, ln2b, yb);
  {
    EpiFF1 e{hb, ffb1};
    gemm_bt<128, EpiFF1><<<dim3(32, 16, 1), 256, 0, stream>>>(yb, wf1T, 2048, 4096, 1024, 0, 0, e);
  }
  {
    EpiFF2 e{out, ffb2, xws};
    gemm_bt<128, EpiFF2><<<dim3(8, 16, 1), 256, 0, stream>>>(hb, wf2T, 2048, 1024, 4096, 0, 0, e);
  }
}